// Round 1
// 410.965 us; speedup vs baseline: 1.2648x; 1.2648x over previous
//
#include <hip/hip_runtime.h>
#include <math.h>

// Problem constants (Posit_Drmm_Modeler)
#define VB  64      // batch
#define NSS 50      // sentences per doc
#define LSS 60      // sentence length
#define LQQ 32      // question length
#define DD  300     // embedding dim
#define FF  256     // filters

#define SEST 312    // seb row stride (bf16): 312%8==0 -> 16B rows; bank step 156%32=28 -> 2-way (free)
#define SROWS 66    // rows 60..65 zero (conv A-frag overrun + M-pad)
#define SCST 264    // scb row stride (bf16): bank step 132%32=4 -> 2-way (free)
#define SIMST 66    // sim row stride (fp32): 2-way on pooling reads
#define KKC 29      // conv K-steps (K=928 incl. stride pads; filter zeros neutralize)
#define KKI 10      // sim_ins K-steps (K=320, qe zero-padded)
#define KKS 8       // sim_sen K-steps (K=256)

typedef __attribute__((ext_vector_type(8))) short bfrag;   // 8 x bf16 (4 VGPRs)
typedef __attribute__((ext_vector_type(4))) float ffrag;   // 4 x f32 acc

__device__ __forceinline__ unsigned short f2bf(float v) {
    unsigned int x = __float_as_uint(v);
    x += 0x7fffu + ((x >> 16) & 1u);          // RNE
    return (unsigned short)(x >> 16);
}
__device__ __forceinline__ float bf2f(unsigned short u) {
    return __uint_as_float(((unsigned int)u) << 16);
}

// ---------------- k_fprep: filters fp32 -> bf16 MFMA B-fragment order
// layout: [kk(29)][nt(16)][lane(64)][j(8)]; value = filt[f=nt*16+(lane&15)][k=kk*32+quad*8+j]
// with k -> (t=k/312, d=k%312), zero if t>=3 or d>=300.
__global__ __launch_bounds__(256) void k_fprep(const float* __restrict__ filters,
                                               unsigned short* __restrict__ filt_frag) {
    int idx = blockIdx.x * 256 + threadIdx.x;
    const int total = KKC * 16 * 64 * 8;
    if (idx >= total) return;
    int j = idx & 7, ln = (idx >> 3) & 63, nt = (idx >> 9) & 15, kk = idx >> 13;
    int f = nt * 16 + (ln & 15);
    int k = kk * 32 + ((ln >> 4) << 3) + j;
    int t = k / SEST, d = k - t * SEST;
    unsigned short v = 0;
    if (t < 3 && d < DD) v = f2bf(filters[f * 900 + t * DD + d]);
    filt_frag[idx] = v;
}

// ---------------- k_qprep (merged): gather qe -> bf16 LDS (stride 312, same as seb),
// q_inv + qe A-fragments, question-conv via MFMA reusing filt_frag, qc_inv + qc A-fragments.
__global__ __launch_bounds__(256) void k_qprep(const int* __restrict__ question,
                                               const float* __restrict__ embeds,
                                               const unsigned short* __restrict__ filt_frag,
                                               unsigned short* __restrict__ qe_frag,
                                               unsigned short* __restrict__ qc_frag,
                                               float* __restrict__ q_inv,
                                               float* __restrict__ qc_inv) {
    const int b = blockIdx.x, tid = threadIdx.x, lane = tid & 63, w = tid >> 6;
    const int quad = lane >> 4, m16 = lane & 15;
    __shared__ __align__(16) unsigned short qeb[34 * SEST];   // 21,216 B (rows 32..33 zero)
    __shared__ __align__(16) unsigned short qcb[LQQ * SCST];  // 16,896 B
    __shared__ int qid[LQQ];
    if (tid < LQQ) qid[tid] = question[b * LQQ + tid];
    {   // zero col tails (rows 0..31, d 300..311) and rows 32..33
        ushort4 z4 = {0, 0, 0, 0};
        for (int i = tid; i < 96; i += 256) {          // 32 rows x 3 ushort4
            int r = i / 3, c = 300 + (i - r * 3) * 4;
            *(ushort4*)(qeb + r * SEST + c) = z4;
        }
        for (int i = tid; i < 156; i += 256) {         // 2 rows x 78 ushort4
            int r = i / 78, c = (i - r * 78) * 4;
            *(ushort4*)(qeb + (LQQ + r) * SEST + c) = z4;
        }
    }
    __syncthreads();
    for (int i = tid; i < LQQ * 75; i += 256) {        // gather -> bf16
        int r = i / 75, c = (i - r * 75) * 4;
        float4 v = *(const float4*)(embeds + (size_t)qid[r] * DD + c);
        ushort4 h;
        h.x = f2bf(v.x); h.y = f2bf(v.y); h.z = f2bf(v.z); h.w = f2bf(v.w);
        *(ushort4*)(qeb + r * SEST + c) = h;
    }
    __syncthreads();
    {   // q_inv from bf16 (8 lanes/row, exactly 256 threads)
        int r = tid >> 3, part = tid & 7;
        float s = 0.f;
        for (int c = part * 4; c < DD; c += 32) {
            uint2 u = *(const uint2*)(qeb + r * SEST + c);
            float a0 = bf2f((unsigned short)(u.x & 0xffff)), a1 = bf2f((unsigned short)(u.x >> 16));
            float a2 = bf2f((unsigned short)(u.y & 0xffff)), a3 = bf2f((unsigned short)(u.y >> 16));
            s += a0 * a0 + a1 * a1 + a2 * a2 + a3 * a3;
        }
        s += __shfl_down(s, 4, 64);
        s += __shfl_down(s, 2, 64);
        s += __shfl_down(s, 1, 64);
        if (part == 0) q_inv[b * LQQ + r] = 1.f / sqrtf(s);
    }
    // qe A-fragments: [kk(10)][mt(2)][lane(64)][j(8)] per b (pure bf16 copy)
    for (int idx = tid; idx < KKI * 2 * 512; idx += 256) {
        int j = idx & 7, ln = (idx >> 3) & 63, mt = (idx >> 9) & 1, kk = idx >> 10;
        int q = mt * 16 + (ln & 15);
        int k = kk * 32 + ((ln >> 4) << 3) + j;
        qe_frag[(size_t)b * (KKI * 2 * 512) + idx] = (k < DD) ? qeb[q * SEST + k] : (unsigned short)0;
    }
    // ===== question conv GEMM: C[q=32][f=256] = qeb-window[32x928] x filt[928x256] =====
    ffrag acc[2][4];
    #pragma unroll
    for (int mt = 0; mt < 2; ++mt)
        #pragma unroll
        for (int i = 0; i < 4; ++i) acc[mt][i] = (ffrag)0.f;
    {
        const bfrag* fF = (const bfrag*)filt_frag;
        const int w4 = w * 4;
        for (int kk = 0; kk < KKC; ++kk) {
            const int kb = kk * 32 + quad * 8;
            bfrag a0 = *(const bfrag*)(qeb + m16 * SEST + kb);
            bfrag a1 = *(const bfrag*)(qeb + (16 + m16) * SEST + kb);
            bfrag bb[4];
            #pragma unroll
            for (int i = 0; i < 4; ++i) bb[i] = fF[(kk * 16 + w4 + i) * 64 + lane];
            #pragma unroll
            for (int i = 0; i < 4; ++i) {
                acc[0][i] = __builtin_amdgcn_mfma_f32_16x16x32_bf16(a0, bb[i], acc[0][i], 0, 0, 0);
                acc[1][i] = __builtin_amdgcn_mfma_f32_16x16x32_bf16(a1, bb[i], acc[1][i], 0, 0, 0);
            }
        }
    }
    // C -> qcb bf16 [q][f]
    #pragma unroll
    for (int mt = 0; mt < 2; ++mt)
        #pragma unroll
        for (int i = 0; i < 4; ++i) {
            int f = (w * 4 + i) * 16 + m16;
            #pragma unroll
            for (int r = 0; r < 4; ++r) {
                int q = mt * 16 + quad * 4 + r;
                qcb[q * SCST + f] = f2bf(acc[mt][i][r]);
            }
        }
    __syncthreads();
    {   // qc_inv from bf16
        int r = tid >> 3, part = tid & 7;
        float s = 0.f;
        for (int c = part * 4; c < FF; c += 32) {
            uint2 u = *(const uint2*)(qcb + r * SCST + c);
            float a0 = bf2f((unsigned short)(u.x & 0xffff)), a1 = bf2f((unsigned short)(u.x >> 16));
            float a2 = bf2f((unsigned short)(u.y & 0xffff)), a3 = bf2f((unsigned short)(u.y >> 16));
            s += a0 * a0 + a1 * a1 + a2 * a2 + a3 * a3;
        }
        s += __shfl_down(s, 4, 64);
        s += __shfl_down(s, 2, 64);
        s += __shfl_down(s, 1, 64);
        if (part == 0) qc_inv[b * LQQ + r] = 1.f / sqrtf(s);
    }
    // qc A-fragments: [kk(8)][mt(2)][lane(64)][j(8)] per b
    for (int idx = tid; idx < KKS * 2 * 512; idx += 256) {
        int j = idx & 7, ln = (idx >> 3) & 63, mt = (idx >> 9) & 1, kk = idx >> 10;
        int q = mt * 16 + (ln & 15);
        int k = kk * 32 + ((ln >> 4) << 3) + j;
        qc_frag[(size_t)b * (KKS * 2 * 512) + idx] = qcb[q * SCST + k];
    }
}

// ---------------- k_sent: fused per-(b,n), 512 threads / 8 waves, 3 blocks/CU -> 24 waves/CU
__global__ __launch_bounds__(512, 6) void k_sent(
    const int* __restrict__ sentences, const int* __restrict__ question,
    const float* __restrict__ embeds,
    const unsigned short* __restrict__ filt_frag,
    const unsigned short* __restrict__ qe_frag,
    const unsigned short* __restrict__ qc_frag,
    const float* __restrict__ q_inv, const float* __restrict__ qc_inv,
    const float* __restrict__ W6, const float* __restrict__ b1,
    float* __restrict__ d_out) {
    const int blk = blockIdx.x;
    const int b = blk / NSS, n = blk - b * NSS;
    const int tid = threadIdx.x, lane = tid & 63, w = tid >> 6;     // w in [0,8)
    const int quad = lane >> 4, m16 = lane & 15;

    __shared__ __align__(16) unsigned short seb[SROWS * SEST]; // 41,184 B; overlaid by scb after conv
    __shared__ __align__(16) float sim[LQQ * SIMST];           // 8,448 B
    __shared__ float sinv[64], scninv[64];
    __shared__ int sid[64];
    __shared__ int qid[LQQ];
    __shared__ float qm[LQQ], qiv[LQQ], qciv[LQQ];
    __shared__ float featq[LQQ][4];
    __shared__ float pr[LQQ];
    unsigned short* scb = seb;   // overlay: conv output [l][f] bf16 (60+4 zero rows x 264)

    if (tid < 64) sid[tid] = (tid < LSS) ? sentences[((size_t)b * NSS + n) * LSS + tid] : 0;
    if (tid < LQQ) {
        int qi = question[b * LQQ + tid];
        qid[tid] = qi; qm[tid] = qi > 0 ? 1.f : 0.f;
        qiv[tid] = q_inv[b * LQQ + tid]; qciv[tid] = qc_inv[b * LQQ + tid];
    }
    // zero seb row tails (d 300..311) and rows 60..65
    {
        ushort4 z4 = {0, 0, 0, 0};
        for (int i = tid; i < 180; i += 512) {
            int r = i / 3, c = 300 + (i - r * 3) * 4;
            *(ushort4*)(seb + r * SEST + c) = z4;
        }
        for (int i = tid; i < 468; i += 512) {
            int r = i / 78, c = (i - r * 78) * 4;
            *(ushort4*)(seb + (60 + r) * SEST + c) = z4;
        }
    }
    __syncthreads();
    // gather sentence embeddings -> bf16 LDS
    for (int i = tid; i < LSS * 75; i += 512) {
        int r = i / 75, c = (i - r * 75) * 4;
        float4 v = *(const float4*)(embeds + (size_t)sid[r] * DD + c);
        ushort4 h;
        h.x = f2bf(v.x); h.y = f2bf(v.y); h.z = f2bf(v.z); h.w = f2bf(v.w);
        *(ushort4*)(seb + r * SEST + c) = h;
    }
    __syncthreads();
    // row inv-norms from bf16 (8 lanes per row, 480 threads)
    if (tid < 480) {
        int r = tid >> 3, part = tid & 7;
        float s = 0.f;
        for (int c = part * 4; c < DD; c += 32) {
            uint2 u = *(const uint2*)(seb + r * SEST + c);
            float a0 = bf2f((unsigned short)(u.x & 0xffff)), a1 = bf2f((unsigned short)(u.x >> 16));
            float a2 = bf2f((unsigned short)(u.y & 0xffff)), a3 = bf2f((unsigned short)(u.y >> 16));
            s += a0 * a0 + a1 * a1 + a2 * a2 + a3 * a3;
        }
        s += __shfl_down(s, 4, 64);
        s += __shfl_down(s, 2, 64);
        s += __shfl_down(s, 1, 64);
        if (part == 0) sinv[r] = 1.f / sqrtf(s);
    }
    if (tid >= 480 && tid < 484) sinv[60 + tid - 480] = 0.f;
    __syncthreads();

    // ======== conv GEMM: C[l=64][f=256] = seb-window[64x928] x filt[928x256] ========
    // wave w owns N-tiles {2w, 2w+1}, all 4 M-tiles. No barriers in K-loop.
    ffrag acc[4][2];
    #pragma unroll
    for (int mt = 0; mt < 4; ++mt)
        #pragma unroll
        for (int i = 0; i < 2; ++i) acc[mt][i] = (ffrag)0.f;
    {
        const bfrag* fF = (const bfrag*)filt_frag;
        const int w2 = w * 2;
        for (int kk = 0; kk < KKC; ++kk) {
            const int kb = kk * 32 + quad * 8;
            bfrag a[4];
            #pragma unroll
            for (int mt = 0; mt < 4; ++mt)
                a[mt] = *(const bfrag*)(seb + (mt * 16 + m16) * SEST + kb);
            bfrag bb[2];
            #pragma unroll
            for (int i = 0; i < 2; ++i)
                bb[i] = fF[(kk * 16 + w2 + i) * 64 + lane];
            #pragma unroll
            for (int mt = 0; mt < 4; ++mt)
                #pragma unroll
                for (int i = 0; i < 2; ++i)
                    acc[mt][i] = __builtin_amdgcn_mfma_f32_16x16x32_bf16(a[mt], bb[i], acc[mt][i], 0, 0, 0);
        }
    }
    // ======== sim_ins GEMM: C[q=32][l=64] = qe[32x320] x seb^T; wave w owns 1 tile ========
    {
        const bfrag* qF = (const bfrag*)qe_frag;
        const int mt = w >> 2, nt = w & 3;
        ffrag c0 = (ffrag)0.f;
        for (int kk = 0; kk < KKI; ++kk) {
            bfrag aq = qF[((size_t)(b * KKI + kk) * 2 + mt) * 64 + lane];
            bfrag b0 = *(const bfrag*)(seb + (nt * 16 + m16) * SEST + kk * 32 + quad * 8);
            c0 = __builtin_amdgcn_mfma_f32_16x16x32_bf16(aq, b0, c0, 0, 0, 0);
        }
        const int l_ = nt * 16 + m16;
        const float sm = sinv[l_] * (sid[l_] > 0 ? 1.f : 0.f);
        #pragma unroll
        for (int r = 0; r < 4; ++r) {
            int q = mt * 16 + quad * 4 + r;
            sim[q * SIMST + l_] = c0[r] * (qiv[q] * qm[q]) * sm;
        }
    }
    __syncthreads();   // all seb reads done; sim_ins visible

    // ======== conv C -> scb bf16 [l][f] (overlays seb) + zero rows 60..63 + pool_ins ========
    if (tid < 256) {
        ushort4 z4 = {0, 0, 0, 0};
        int r4 = 60 + (tid >> 6), c4 = (tid & 63) * 4;
        *(ushort4*)(scb + r4 * SCST + c4) = z4;
    }
    #pragma unroll
    for (int mt = 0; mt < 4; ++mt)
        #pragma unroll
        for (int i = 0; i < 2; ++i) {
            int f = (w * 2 + i) * 16 + m16;
            #pragma unroll
            for (int r = 0; r < 4; ++r) {
                int l = mt * 16 + quad * 4 + r;
                scb[l * SCST + f] = f2bf(acc[mt][i][r]);
            }
        }
    if (tid < LQQ) {   // pool_ins + exact-match channel (integer equality, incl pad==pad, unmasked)
        int q = tid;
        float t0 = -1e30f, t1 = -1e30f, t2 = -1e30f, t3 = -1e30f, t4 = -1e30f;
        for (int l = 0; l < LSS; ++l) {
            float v = sim[q * SIMST + l];
            if (v > t4) {
                if (v > t0)      { t4 = t3; t3 = t2; t2 = t1; t1 = t0; t0 = v; }
                else if (v > t1) { t4 = t3; t3 = t2; t2 = t1; t1 = v; }
                else if (v > t2) { t4 = t3; t3 = t2; t2 = v; }
                else if (v > t3) { t4 = t3; t3 = v; }
                else               t4 = v;
            }
        }
        featq[q][0] = t0;
        featq[q][1] = (t0 + t1 + t2 + t3 + t4) * 0.2f;
        int qi = qid[q], c = 0;
        for (int l = 0; l < LSS; ++l) c += (sid[l] == qi) ? 1 : 0;
        featq[q][2] = c > 0 ? 1.f : 0.f;
        featq[q][3] = (float)(c < 5 ? c : 5) * 0.2f;
    }
    __syncthreads();
    // scb row inv-norms (8 lanes per row, 480 threads)
    if (tid < 480) {
        int r = tid >> 3, part = tid & 7;
        float s = 0.f;
        for (int c = part * 4; c < FF; c += 32) {
            uint2 u = *(const uint2*)(scb + r * SCST + c);
            float a0 = bf2f((unsigned short)(u.x & 0xffff)), a1 = bf2f((unsigned short)(u.x >> 16));
            float a2 = bf2f((unsigned short)(u.y & 0xffff)), a3 = bf2f((unsigned short)(u.y >> 16));
            s += a0 * a0 + a1 * a1 + a2 * a2 + a3 * a3;
        }
        s += __shfl_down(s, 4, 64);
        s += __shfl_down(s, 2, 64);
        s += __shfl_down(s, 1, 64);
        if (part == 0) scninv[r] = 1.f / sqrtf(s);
    }
    if (tid >= 480 && tid < 484) scninv[60 + tid - 480] = 0.f;
    __syncthreads();
    // ======== sim_sen GEMM: C[q=32][l=64] = qc[32x256] x scb^T; wave w owns 1 tile ========
    {
        const bfrag* qF = (const bfrag*)qc_frag;
        const int mt = w >> 2, nt = w & 3;
        ffrag c0 = (ffrag)0.f;
        for (int kk = 0; kk < KKS; ++kk) {
            bfrag aq = qF[((size_t)(b * KKS + kk) * 2 + mt) * 64 + lane];
            bfrag b0 = *(const bfrag*)(scb + (nt * 16 + m16) * SCST + kk * 32 + quad * 8);
            c0 = __builtin_amdgcn_mfma_f32_16x16x32_bf16(aq, b0, c0, 0, 0, 0);
        }
        const int l_ = nt * 16 + m16;
        const float sm = scninv[l_] * (sid[l_] > 0 ? 1.f : 0.f);
        #pragma unroll
        for (int r = 0; r < 4; ++r) {
            int q = mt * 16 + quad * 4 + r;
            sim[q * SIMST + l_] = c0[r] * (qciv[q] * qm[q]) * sm;
        }
    }
    __syncthreads();
    if (tid < LQQ) {   // pool_sen + linear + sigmoid
        int q = tid;
        float t0 = -1e30f, t1 = -1e30f, t2 = -1e30f, t3 = -1e30f, t4 = -1e30f;
        for (int l = 0; l < LSS; ++l) {
            float v = sim[q * SIMST + l];
            if (v > t4) {
                if (v > t0)      { t4 = t3; t3 = t2; t2 = t1; t1 = t0; t0 = v; }
                else if (v > t1) { t4 = t3; t3 = t2; t2 = t1; t1 = v; }
                else if (v > t2) { t4 = t3; t3 = t2; t2 = v; }
                else if (v > t3) { t4 = t3; t3 = v; }
                else               t4 = v;
            }
        }
        float smax = t0, smean = (t0 + t1 + t2 + t3 + t4) * 0.2f;
        float z = featq[q][0] * W6[0] + featq[q][1] * W6[1] + smax * W6[2] + smean * W6[3]
                + featq[q][2] * W6[4] + featq[q][3] * W6[5] + b1[0];
        pr[q] = 1.f / (1.f + expf(-z));
    }
    __syncthreads();
    if (w == 0) {
        float s = (lane < LQQ) ? pr[lane] : 0.f;
        s += __shfl_down(s, 16, 64);
        s += __shfl_down(s, 8, 64);
        s += __shfl_down(s, 4, 64);
        s += __shfl_down(s, 2, 64);
        s += __shfl_down(s, 1, 64);
        if (lane == 0) d_out[1 + (size_t)b * NSS + n] = s * (1.f / 32.f);
    }
}

// ---------------- k_final: doc max + both BCEs + loss
__global__ __launch_bounds__(256) void k_final(const int* __restrict__ tsent,
                                               const int* __restrict__ tdoc,
                                               float* __restrict__ d_out) {
    const int tid = threadIdx.x;
    __shared__ float sh[256];
    __shared__ float docs[VB];
    if (tid < VB) {
        float m = -1e30f;
        for (int nn = 0; nn < NSS; ++nn) m = fmaxf(m, d_out[1 + tid * NSS + nn]);
        docs[tid] = m;
        d_out[1 + VB * NSS + tid] = m;
    }
    float s = 0.f;
    for (int i = tid; i < VB * NSS; i += 256) {
        float p = d_out[1 + i];
        p = fminf(fmaxf(p, 1e-7f), 1.f - 1e-7f);
        float t = (float)tsent[i];
        s += t * logf(p) + (1.f - t) * log1pf(-p);
    }
    sh[tid] = s;
    __syncthreads();
    for (int st = 128; st > 0; st >>= 1) {
        if (tid < st) sh[tid] += sh[tid + st];
        __syncthreads();
    }
    float ls = 0.f;
    if (tid == 0) ls = -sh[0] / (float)(VB * NSS);
    __syncthreads();
    float s2 = 0.f;
    if (tid < VB) {
        float p = fminf(fmaxf(docs[tid], 1e-7f), 1.f - 1e-7f);
        float t = (float)tdoc[tid];
        s2 = t * logf(p) + (1.f - t) * log1pf(-p);
    }
    sh[tid] = s2;
    __syncthreads();
    for (int st = 128; st > 0; st >>= 1) {
        if (tid < st) sh[tid] += sh[tid + st];
        __syncthreads();
    }
    if (tid == 0) {
        float ld = -sh[0] / (float)VB;
        d_out[0] = 0.5f * (ls + ld);
    }
}

extern "C" void kernel_launch(void* const* d_in, const int* in_sizes, int n_in,
                              void* d_out, int out_size, void* d_ws, size_t ws_size,
                              hipStream_t stream) {
    const int*   sentences = (const int*)d_in[0];
    const int*   question  = (const int*)d_in[1];
    const int*   tsent     = (const int*)d_in[2];
    const int*   tdoc      = (const int*)d_in[3];
    const float* embeds    = (const float*)d_in[4];
    const float* filters   = (const float*)d_in[5];
    const float* W6        = (const float*)d_in[6];
    const float* b1        = (const float*)d_in[7];
    float* out = (float*)d_out;

    float* ws = (float*)d_ws;
    float* q_inv  = ws;                         // 2,048 f
    float* qc_inv = ws + 2048;                  // 2,048 f
    unsigned short* qe_frag  = (unsigned short*)(ws + 4096);      // 655,360 sh (16B-aligned)
    unsigned short* qc_frag  = qe_frag + 655360;                  // 524,288 sh
    unsigned short* filt_frag = qc_frag + 524288;                 // 237,568 sh  (total ~2.85 MB)

    k_fprep<<<928, 256, 0, stream>>>(filters, filt_frag);
    k_qprep<<<VB, 256, 0, stream>>>(question, embeds, filt_frag, qe_frag, qc_frag, q_inv, qc_inv);
    k_sent<<<VB * NSS, 512, 0, stream>>>(sentences, question, embeds,
                                         filt_frag, qe_frag, qc_frag,
                                         q_inv, qc_inv, W6, b1, out);
    k_final<<<1, 256, 0, stream>>>(tsent, tdoc, out);
}

// Round 2
// 401.791 us; speedup vs baseline: 1.2937x; 1.0228x over previous
//
#include <hip/hip_runtime.h>
#include <math.h>

// Problem constants (Posit_Drmm_Modeler)
#define VB  64      // batch
#define NSS 50      // sentences per doc
#define LSS 60      // sentence length
#define LQQ 32      // question length
#define DD  300     // embedding dim
#define FF  256     // filters

#define SEST 312    // seb row stride (bf16): 312%8==0 -> 16B rows; bank step 156%32=28 -> 2-way (free)
#define SROWS 66    // rows 60..65 zero (conv A-frag overrun + M-pad)
#define SCST 264    // scb row stride (bf16): bank step 132%32=4 -> 2-way (free)
#define SIMST 66    // sim row stride (fp32): 2-way on pooling reads
#define KKC 29      // conv K-steps (K=928 incl. stride pads; filter zeros neutralize)
#define KKI 10      // sim_ins K-steps (K=320, qe zero-padded)
#define KKS 8       // sim_sen K-steps (K=256)

typedef __attribute__((ext_vector_type(8))) short bfrag;   // 8 x bf16 (4 VGPRs)
typedef __attribute__((ext_vector_type(4))) float ffrag;   // 4 x f32 acc

__device__ __forceinline__ unsigned short f2bf(float v) {
    unsigned int x = __float_as_uint(v);
    x += 0x7fffu + ((x >> 16) & 1u);          // RNE
    return (unsigned short)(x >> 16);
}
__device__ __forceinline__ float bf2f(unsigned short u) {
    return __uint_as_float(((unsigned int)u) << 16);
}

// ---------------- k_fprep: filters fp32 -> bf16 MFMA B-fragment order
// layout: [kk(29)][nt(16)][lane(64)][j(8)]; value = filt[f=nt*16+(lane&15)][k=kk*32+quad*8+j]
// with k -> (t=k/312, d=k%312), zero if t>=3 or d>=300.
__global__ __launch_bounds__(256) void k_fprep(const float* __restrict__ filters,
                                               unsigned short* __restrict__ filt_frag) {
    int idx = blockIdx.x * 256 + threadIdx.x;
    const int total = KKC * 16 * 64 * 8;
    if (idx >= total) return;
    int j = idx & 7, ln = (idx >> 3) & 63, nt = (idx >> 9) & 15, kk = idx >> 13;
    int f = nt * 16 + (ln & 15);
    int k = kk * 32 + ((ln >> 4) << 3) + j;
    int t = k / SEST, d = k - t * SEST;
    unsigned short v = 0;
    if (t < 3 && d < DD) v = f2bf(filters[f * 900 + t * DD + d]);
    filt_frag[idx] = v;
}

// ---------------- k_qprep (merged, 512 thr): gather qe -> bf16 LDS (stride 312),
// q_inv + qe A-fragments, question-conv via MFMA reusing filt_frag, qc_inv + qc A-fragments.
__global__ __launch_bounds__(512) void k_qprep(const int* __restrict__ question,
                                               const float* __restrict__ embeds,
                                               const unsigned short* __restrict__ filt_frag,
                                               unsigned short* __restrict__ qe_frag,
                                               unsigned short* __restrict__ qc_frag,
                                               float* __restrict__ q_inv,
                                               float* __restrict__ qc_inv) {
    const int b = blockIdx.x, tid = threadIdx.x, lane = tid & 63, w = tid >> 6;
    const int quad = lane >> 4, m16 = lane & 15;
    __shared__ __align__(16) unsigned short qeb[34 * SEST];   // 21,216 B (rows 32..33 zero)
    __shared__ __align__(16) unsigned short qcb[LQQ * SCST];  // 16,896 B
    const int* qrow = question + b * LQQ;
    {   // zero col tails (rows 0..31, d 300..311) and rows 32..33
        ushort4 z4 = {0, 0, 0, 0};
        for (int i = tid; i < 96; i += 512) {
            int r = i / 3, c = 300 + (i - r * 3) * 4;
            *(ushort4*)(qeb + r * SEST + c) = z4;
        }
        for (int i = tid; i < 156; i += 512) {
            int r = i / 78, c = (i - r * 78) * 4;
            *(ushort4*)(qeb + (LQQ + r) * SEST + c) = z4;
        }
    }
    for (int i = tid; i < LQQ * 75; i += 512) {        // gather -> bf16 (ids direct from global)
        int r = i / 75, c = (i - r * 75) * 4;
        float4 v = *(const float4*)(embeds + (size_t)qrow[r] * DD + c);
        ushort4 h;
        h.x = f2bf(v.x); h.y = f2bf(v.y); h.z = f2bf(v.z); h.w = f2bf(v.w);
        *(ushort4*)(qeb + r * SEST + c) = h;
    }
    __syncthreads();
    if (tid < 256) {   // q_inv from bf16 (8 lanes/row), b128 reads
        int r = tid >> 3, part = tid & 7;
        float s = 0.f;
        #pragma unroll
        for (int it = 0; it < 5; ++it) {
            if (!(it == 4 && part == 7)) {
                int c = part * 8 + it * 64;
                uint4 u = *(const uint4*)(qeb + r * SEST + c);
                float a0 = bf2f((unsigned short)(u.x & 0xffff)), a1 = bf2f((unsigned short)(u.x >> 16));
                float a2 = bf2f((unsigned short)(u.y & 0xffff)), a3 = bf2f((unsigned short)(u.y >> 16));
                float a4 = bf2f((unsigned short)(u.z & 0xffff)), a5 = bf2f((unsigned short)(u.z >> 16));
                float a6 = bf2f((unsigned short)(u.w & 0xffff)), a7 = bf2f((unsigned short)(u.w >> 16));
                s += a0 * a0 + a1 * a1 + a2 * a2 + a3 * a3 + a4 * a4 + a5 * a5 + a6 * a6 + a7 * a7;
            }
        }
        s += __shfl_down(s, 4, 64);
        s += __shfl_down(s, 2, 64);
        s += __shfl_down(s, 1, 64);
        if (part == 0) q_inv[b * LQQ + r] = 1.f / sqrtf(s);
    }
    // qe A-fragments: [kk(10)][mt(2)][lane(64)][j(8)] per b (pure bf16 copy)
    for (int idx = tid; idx < KKI * 2 * 512; idx += 512) {
        int j = idx & 7, ln = (idx >> 3) & 63, mt = (idx >> 9) & 1, kk = idx >> 10;
        int q = mt * 16 + (ln & 15);
        int k = kk * 32 + ((ln >> 4) << 3) + j;
        qe_frag[(size_t)b * (KKI * 2 * 512) + idx] = (k < DD) ? qeb[q * SEST + k] : (unsigned short)0;
    }
    // ===== question conv GEMM: C[q=32][f=256] = qeb-window[32x928] x filt[928x256] =====
    // 8 waves: wave w owns M-tile (w&1), N-tiles (w>>1)*4 .. +3
    const int mtq = w & 1, w4 = (w >> 1) * 4;
    ffrag acc[4];
    #pragma unroll
    for (int i = 0; i < 4; ++i) acc[i] = (ffrag)0.f;
    {
        const bfrag* fF = (const bfrag*)filt_frag;
        for (int kk = 0; kk < KKC; ++kk) {
            const int kb = kk * 32 + quad * 8;
            bfrag a0 = *(const bfrag*)(qeb + (mtq * 16 + m16) * SEST + kb);
            bfrag bb[4];
            #pragma unroll
            for (int i = 0; i < 4; ++i) bb[i] = fF[(kk * 16 + w4 + i) * 64 + lane];
            #pragma unroll
            for (int i = 0; i < 4; ++i)
                acc[i] = __builtin_amdgcn_mfma_f32_16x16x32_bf16(a0, bb[i], acc[i], 0, 0, 0);
        }
    }
    // C -> qcb bf16 [q][f]
    #pragma unroll
    for (int i = 0; i < 4; ++i) {
        int f = (w4 + i) * 16 + m16;
        #pragma unroll
        for (int r = 0; r < 4; ++r) {
            int q = mtq * 16 + quad * 4 + r;
            qcb[q * SCST + f] = f2bf(acc[i][r]);
        }
    }
    __syncthreads();
    if (tid < 256) {   // qc_inv from bf16, b128 reads (FF=256 = 4 full iters)
        int r = tid >> 3, part = tid & 7;
        float s = 0.f;
        #pragma unroll
        for (int it = 0; it < 4; ++it) {
            int c = part * 8 + it * 64;
            uint4 u = *(const uint4*)(qcb + r * SCST + c);
            float a0 = bf2f((unsigned short)(u.x & 0xffff)), a1 = bf2f((unsigned short)(u.x >> 16));
            float a2 = bf2f((unsigned short)(u.y & 0xffff)), a3 = bf2f((unsigned short)(u.y >> 16));
            float a4 = bf2f((unsigned short)(u.z & 0xffff)), a5 = bf2f((unsigned short)(u.z >> 16));
            float a6 = bf2f((unsigned short)(u.w & 0xffff)), a7 = bf2f((unsigned short)(u.w >> 16));
            s += a0 * a0 + a1 * a1 + a2 * a2 + a3 * a3 + a4 * a4 + a5 * a5 + a6 * a6 + a7 * a7;
        }
        s += __shfl_down(s, 4, 64);
        s += __shfl_down(s, 2, 64);
        s += __shfl_down(s, 1, 64);
        if (part == 0) qc_inv[b * LQQ + r] = 1.f / sqrtf(s);
    }
    // qc A-fragments: [kk(8)][mt(2)][lane(64)][j(8)] per b
    for (int idx = tid; idx < KKS * 2 * 512; idx += 512) {
        int j = idx & 7, ln = (idx >> 3) & 63, mt = (idx >> 9) & 1, kk = idx >> 10;
        int q = mt * 16 + (ln & 15);
        int k = kk * 32 + ((ln >> 4) << 3) + j;
        qc_frag[(size_t)b * (KKS * 2 * 512) + idx] = qcb[q * SCST + k];
    }
}

// one conv K-step: 4 A-frags from LDS + 8 MFMA with prefetched B regs
#define CONV_STEP(KKV, BB0, BB1) do {                                              \
    const int kb_ = (KKV) * 32 + quad * 8;                                         \
    bfrag a0_ = *(const bfrag*)(seb + (m16) * SEST + kb_);                         \
    bfrag a1_ = *(const bfrag*)(seb + (16 + m16) * SEST + kb_);                    \
    bfrag a2_ = *(const bfrag*)(seb + (32 + m16) * SEST + kb_);                    \
    bfrag a3_ = *(const bfrag*)(seb + (48 + m16) * SEST + kb_);                    \
    __builtin_amdgcn_s_setprio(1);                                                 \
    acc[0][0] = __builtin_amdgcn_mfma_f32_16x16x32_bf16(a0_, BB0, acc[0][0], 0, 0, 0); \
    acc[0][1] = __builtin_amdgcn_mfma_f32_16x16x32_bf16(a0_, BB1, acc[0][1], 0, 0, 0); \
    acc[1][0] = __builtin_amdgcn_mfma_f32_16x16x32_bf16(a1_, BB0, acc[1][0], 0, 0, 0); \
    acc[1][1] = __builtin_amdgcn_mfma_f32_16x16x32_bf16(a1_, BB1, acc[1][1], 0, 0, 0); \
    acc[2][0] = __builtin_amdgcn_mfma_f32_16x16x32_bf16(a2_, BB0, acc[2][0], 0, 0, 0); \
    acc[2][1] = __builtin_amdgcn_mfma_f32_16x16x32_bf16(a2_, BB1, acc[2][1], 0, 0, 0); \
    acc[3][0] = __builtin_amdgcn_mfma_f32_16x16x32_bf16(a3_, BB0, acc[3][0], 0, 0, 0); \
    acc[3][1] = __builtin_amdgcn_mfma_f32_16x16x32_bf16(a3_, BB1, acc[3][1], 0, 0, 0); \
    __builtin_amdgcn_s_setprio(0);                                                 \
} while (0)

// ---------------- k_sent: fused per-(b,n), 512 threads / 8 waves, 3 blocks/CU
__global__ __launch_bounds__(512, 6) void k_sent(
    const int* __restrict__ sentences, const int* __restrict__ question,
    const float* __restrict__ embeds,
    const unsigned short* __restrict__ filt_frag,
    const unsigned short* __restrict__ qe_frag,
    const unsigned short* __restrict__ qc_frag,
    const float* __restrict__ q_inv, const float* __restrict__ qc_inv,
    const float* __restrict__ W6, const float* __restrict__ b1,
    float* __restrict__ d_out) {
    const int blk = blockIdx.x;
    const int b = blk / NSS, n = blk - b * NSS;
    const int tid = threadIdx.x, lane = tid & 63, w = tid >> 6;     // w in [0,8)
    const int quad = lane >> 4, m16 = lane & 15;
    const int w2 = w * 2;

    __shared__ __align__(16) unsigned short seb[SROWS * SEST]; // 41,184 B; overlaid by scb after conv
    __shared__ __align__(16) float sim[LQQ * SIMST];           // 8,448 B
    __shared__ float sinv[64], scninv[64];
    __shared__ int sid[64];
    __shared__ int qid[LQQ];
    __shared__ float qm[LQQ], qiv[LQQ], qciv[LQQ];
    __shared__ float featq[LQQ][4];
    __shared__ float pr[LQQ];
    unsigned short* scb = seb;   // overlay: conv output [l][f] bf16 (60+4 zero rows x 264)

    // early prefetch of first conv B-fragments (independent of LDS)
    const bfrag* fF = (const bfrag*)filt_frag;
    bfrag b0a = fF[(w2) * 64 + lane];
    bfrag b0b = fF[(w2 + 1) * 64 + lane];

    const int* srow = sentences + ((size_t)b * NSS + n) * LSS;
    if (tid < 64) sid[tid] = (tid < LSS) ? srow[tid] : 0;
    if (tid < LQQ) {
        int qi = question[b * LQQ + tid];
        qid[tid] = qi; qm[tid] = qi > 0 ? 1.f : 0.f;
        qiv[tid] = q_inv[b * LQQ + tid]; qciv[tid] = qc_inv[b * LQQ + tid];
    }
    // zero seb row tails (d 300..311) and rows 60..65 (disjoint from gather region -> no barrier)
    {
        ushort4 z4 = {0, 0, 0, 0};
        for (int i = tid; i < 180; i += 512) {
            int r = i / 3, c = 300 + (i - r * 3) * 4;
            *(ushort4*)(seb + r * SEST + c) = z4;
        }
        for (int i = tid; i < 468; i += 512) {
            int r = i / 78, c = (i - r * 78) * 4;
            *(ushort4*)(seb + (60 + r) * SEST + c) = z4;
        }
    }
    // gather sentence embeddings -> bf16 LDS (token ids direct from global; L1-hot)
    for (int i = tid; i < LSS * 75; i += 512) {
        int r = i / 75, c = (i - r * 75) * 4;
        float4 v = *(const float4*)(embeds + (size_t)srow[r] * DD + c);
        ushort4 h;
        h.x = f2bf(v.x); h.y = f2bf(v.y); h.z = f2bf(v.z); h.w = f2bf(v.w);
        *(ushort4*)(seb + r * SEST + c) = h;
    }
    __syncthreads();
    // row inv-norms from bf16 (8 lanes/row, 480 threads), b128 reads
    if (tid < 480) {
        int r = tid >> 3, part = tid & 7;
        float s = 0.f;
        #pragma unroll
        for (int it = 0; it < 5; ++it) {
            if (!(it == 4 && part == 7)) {       // c=312 would cross into next row
                int c = part * 8 + it * 64;      // tails 300..311 are zero -> safe
                uint4 u = *(const uint4*)(seb + r * SEST + c);
                float a0 = bf2f((unsigned short)(u.x & 0xffff)), a1 = bf2f((unsigned short)(u.x >> 16));
                float a2 = bf2f((unsigned short)(u.y & 0xffff)), a3 = bf2f((unsigned short)(u.y >> 16));
                float a4 = bf2f((unsigned short)(u.z & 0xffff)), a5 = bf2f((unsigned short)(u.z >> 16));
                float a6 = bf2f((unsigned short)(u.w & 0xffff)), a7 = bf2f((unsigned short)(u.w >> 16));
                s += a0 * a0 + a1 * a1 + a2 * a2 + a3 * a3 + a4 * a4 + a5 * a5 + a6 * a6 + a7 * a7;
            }
        }
        s += __shfl_down(s, 4, 64);
        s += __shfl_down(s, 2, 64);
        s += __shfl_down(s, 1, 64);
        if (part == 0) sinv[r] = 1.f / sqrtf(s);
    }
    if (tid >= 480 && tid < 484) sinv[60 + tid - 480] = 0.f;
    __syncthreads();

    // ======== conv GEMM: C[l=64][f=256] = seb-window[64x928] x filt[928x256] ========
    // wave w owns N-tiles {2w, 2w+1}, all 4 M-tiles. Software-pipelined B prefetch (unroll-2).
    ffrag acc[4][2];
    #pragma unroll
    for (int mt = 0; mt < 4; ++mt)
        #pragma unroll
        for (int i = 0; i < 2; ++i) acc[mt][i] = (ffrag)0.f;
    {
        bfrag b1a, b1b;
        for (int kk = 0; kk + 2 <= KKC; kk += 2) {
            b1a = fF[((kk + 1) * 16 + w2) * 64 + lane];
            b1b = fF[((kk + 1) * 16 + w2 + 1) * 64 + lane];
            CONV_STEP(kk, b0a, b0b);
            if (kk + 2 < KKC) {
                b0a = fF[((kk + 2) * 16 + w2) * 64 + lane];
                b0b = fF[((kk + 2) * 16 + w2 + 1) * 64 + lane];
            }
            CONV_STEP(kk + 1, b1a, b1b);
        }
        CONV_STEP(KKC - 1, b0a, b0b);   // kk=28, loaded during kk=26 pair
    }
    // ======== sim_ins GEMM: C[q=32][l=64] = qe[32x320] x seb^T; wave w owns 1 tile ========
    {
        const int mt = w >> 2, nt = w & 3;
        const bfrag* qF = (const bfrag*)qe_frag + ((size_t)b * KKI * 2 + mt) * 64 + lane;
        const unsigned short* sebr = seb + (nt * 16 + m16) * SEST + quad * 8;
        ffrag c0 = (ffrag)0.f;
        bfrag aq0 = qF[0];
        for (int kk = 0; kk < KKI; kk += 2) {
            bfrag aq1 = qF[(kk + 1) * 128];
            bfrag bL0 = *(const bfrag*)(sebr + kk * 32);
            c0 = __builtin_amdgcn_mfma_f32_16x16x32_bf16(aq0, bL0, c0, 0, 0, 0);
            if (kk + 2 < KKI) aq0 = qF[(kk + 2) * 128];
            bfrag bL1 = *(const bfrag*)(sebr + (kk + 1) * 32);
            c0 = __builtin_amdgcn_mfma_f32_16x16x32_bf16(aq1, bL1, c0, 0, 0, 0);
        }
        const int l_ = nt * 16 + m16;
        const float sm = sinv[l_] * (sid[l_] > 0 ? 1.f : 0.f);
        #pragma unroll
        for (int r = 0; r < 4; ++r) {
            int q = mt * 16 + quad * 4 + r;
            sim[q * SIMST + l_] = c0[r] * (qiv[q] * qm[q]) * sm;
        }
    }
    __syncthreads();   // all seb reads done; sim_ins visible

    // ======== conv C -> scb bf16 [l][f] (overlays seb) + zero rows 60..63 + pool_ins ========
    if (tid < 256) {
        ushort4 z4 = {0, 0, 0, 0};
        int r4 = 60 + (tid >> 6), c4 = (tid & 63) * 4;
        *(ushort4*)(scb + r4 * SCST + c4) = z4;
    }
    #pragma unroll
    for (int mt = 0; mt < 4; ++mt)
        #pragma unroll
        for (int i = 0; i < 2; ++i) {
            int f = (w2 + i) * 16 + m16;
            #pragma unroll
            for (int r = 0; r < 4; ++r) {
                int l = mt * 16 + quad * 4 + r;
                scb[l * SCST + f] = f2bf(acc[mt][i][r]);
            }
        }
    if (tid < LQQ) {   // pool_ins + exact-match channel (integer equality, incl pad==pad, unmasked)
        int q = tid;
        float t0 = -1e30f, t1 = -1e30f, t2 = -1e30f, t3 = -1e30f, t4 = -1e30f;
        for (int l = 0; l < LSS; ++l) {
            float v = sim[q * SIMST + l];
            if (v > t4) {
                if (v > t0)      { t4 = t3; t3 = t2; t2 = t1; t1 = t0; t0 = v; }
                else if (v > t1) { t4 = t3; t3 = t2; t2 = t1; t1 = v; }
                else if (v > t2) { t4 = t3; t3 = t2; t2 = v; }
                else if (v > t3) { t4 = t3; t3 = v; }
                else               t4 = v;
            }
        }
        featq[q][0] = t0;
        featq[q][1] = (t0 + t1 + t2 + t3 + t4) * 0.2f;
        int qi = qid[q], c = 0;
        for (int l = 0; l < LSS; ++l) c += (sid[l] == qi) ? 1 : 0;
        featq[q][2] = c > 0 ? 1.f : 0.f;
        featq[q][3] = (float)(c < 5 ? c : 5) * 0.2f;
    }
    __syncthreads();
    // scb row inv-norms (8 lanes/row, 480 threads), b128 reads (FF=256 = 4 full iters)
    if (tid < 480) {
        int r = tid >> 3, part = tid & 7;
        float s = 0.f;
        #pragma unroll
        for (int it = 0; it < 4; ++it) {
            int c = part * 8 + it * 64;
            uint4 u = *(const uint4*)(scb + r * SCST + c);
            float a0 = bf2f((unsigned short)(u.x & 0xffff)), a1 = bf2f((unsigned short)(u.x >> 16));
            float a2 = bf2f((unsigned short)(u.y & 0xffff)), a3 = bf2f((unsigned short)(u.y >> 16));
            float a4 = bf2f((unsigned short)(u.z & 0xffff)), a5 = bf2f((unsigned short)(u.z >> 16));
            float a6 = bf2f((unsigned short)(u.w & 0xffff)), a7 = bf2f((unsigned short)(u.w >> 16));
            s += a0 * a0 + a1 * a1 + a2 * a2 + a3 * a3 + a4 * a4 + a5 * a5 + a6 * a6 + a7 * a7;
        }
        s += __shfl_down(s, 4, 64);
        s += __shfl_down(s, 2, 64);
        s += __shfl_down(s, 1, 64);
        if (part == 0) scninv[r] = 1.f / sqrtf(s);
    }
    if (tid >= 480 && tid < 484) scninv[60 + tid - 480] = 0.f;
    __syncthreads();
    // ======== sim_sen GEMM: C[q=32][l=64] = qc[32x256] x scb^T; wave w owns 1 tile ========
    {
        const int mt = w >> 2, nt = w & 3;
        const bfrag* qF = (const bfrag*)qc_frag + ((size_t)b * KKS * 2 + mt) * 64 + lane;
        const unsigned short* scbr = scb + (nt * 16 + m16) * SCST + quad * 8;
        ffrag c0 = (ffrag)0.f;
        bfrag aq0 = qF[0];
        for (int kk = 0; kk < KKS; kk += 2) {
            bfrag aq1 = qF[(kk + 1) * 128];
            bfrag bL0 = *(const bfrag*)(scbr + kk * 32);
            c0 = __builtin_amdgcn_mfma_f32_16x16x32_bf16(aq0, bL0, c0, 0, 0, 0);
            if (kk + 2 < KKS) aq0 = qF[(kk + 2) * 128];
            bfrag bL1 = *(const bfrag*)(scbr + (kk + 1) * 32);
            c0 = __builtin_amdgcn_mfma_f32_16x16x32_bf16(aq1, bL1, c0, 0, 0, 0);
        }
        const int l_ = nt * 16 + m16;
        const float sm = scninv[l_] * (sid[l_] > 0 ? 1.f : 0.f);
        #pragma unroll
        for (int r = 0; r < 4; ++r) {
            int q = mt * 16 + quad * 4 + r;
            sim[q * SIMST + l_] = c0[r] * (qciv[q] * qm[q]) * sm;
        }
    }
    __syncthreads();
    if (tid < LQQ) {   // pool_sen + linear + sigmoid
        int q = tid;
        float t0 = -1e30f, t1 = -1e30f, t2 = -1e30f, t3 = -1e30f, t4 = -1e30f;
        for (int l = 0; l < LSS; ++l) {
            float v = sim[q * SIMST + l];
            if (v > t4) {
                if (v > t0)      { t4 = t3; t3 = t2; t2 = t1; t1 = t0; t0 = v; }
                else if (v > t1) { t4 = t3; t3 = t2; t2 = t1; t1 = v; }
                else if (v > t2) { t4 = t3; t3 = t2; t2 = v; }
                else if (v > t3) { t4 = t3; t3 = v; }
                else               t4 = v;
            }
        }
        float smax = t0, smean = (t0 + t1 + t2 + t3 + t4) * 0.2f;
        float z = featq[q][0] * W6[0] + featq[q][1] * W6[1] + smax * W6[2] + smean * W6[3]
                + featq[q][2] * W6[4] + featq[q][3] * W6[5] + b1[0];
        pr[q] = 1.f / (1.f + expf(-z));
    }
    __syncthreads();
    if (w == 0) {
        float s = (lane < LQQ) ? pr[lane] : 0.f;
        s += __shfl_down(s, 16, 64);
        s += __shfl_down(s, 8, 64);
        s += __shfl_down(s, 4, 64);
        s += __shfl_down(s, 2, 64);
        s += __shfl_down(s, 1, 64);
        if (lane == 0) d_out[1 + (size_t)b * NSS + n] = s * (1.f / 32.f);
    }
}

// ---------------- k_final: doc max + both BCEs + loss
__global__ __launch_bounds__(256) void k_final(const int* __restrict__ tsent,
                                               const int* __restrict__ tdoc,
                                               float* __restrict__ d_out) {
    const int tid = threadIdx.x;
    __shared__ float sh[256];
    __shared__ float docs[VB];
    if (tid < VB) {
        float m = -1e30f;
        for (int nn = 0; nn < NSS; ++nn) m = fmaxf(m, d_out[1 + tid * NSS + nn]);
        docs[tid] = m;
        d_out[1 + VB * NSS + tid] = m;
    }
    float s = 0.f;
    for (int i = tid; i < VB * NSS; i += 256) {
        float p = d_out[1 + i];
        p = fminf(fmaxf(p, 1e-7f), 1.f - 1e-7f);
        float t = (float)tsent[i];
        s += t * logf(p) + (1.f - t) * log1pf(-p);
    }
    sh[tid] = s;
    __syncthreads();
    for (int st = 128; st > 0; st >>= 1) {
        if (tid < st) sh[tid] += sh[tid + st];
        __syncthreads();
    }
    float ls = 0.f;
    if (tid == 0) ls = -sh[0] / (float)(VB * NSS);
    __syncthreads();
    float s2 = 0.f;
    if (tid < VB) {
        float p = fminf(fmaxf(docs[tid], 1e-7f), 1.f - 1e-7f);
        float t = (float)tdoc[tid];
        s2 = t * logf(p) + (1.f - t) * log1pf(-p);
    }
    sh[tid] = s2;
    __syncthreads();
    for (int st = 128; st > 0; st >>= 1) {
        if (tid < st) sh[tid] += sh[tid + st];
        __syncthreads();
    }
    if (tid == 0) {
        float ld = -sh[0] / (float)VB;
        d_out[0] = 0.5f * (ls + ld);
    }
}

extern "C" void kernel_launch(void* const* d_in, const int* in_sizes, int n_in,
                              void* d_out, int out_size, void* d_ws, size_t ws_size,
                              hipStream_t stream) {
    const int*   sentences = (const int*)d_in[0];
    const int*   question  = (const int*)d_in[1];
    const int*   tsent     = (const int*)d_in[2];
    const int*   tdoc      = (const int*)d_in[3];
    const float* embeds    = (const float*)d_in[4];
    const float* filters   = (const float*)d_in[5];
    const float* W6        = (const float*)d_in[6];
    const float* b1        = (const float*)d_in[7];
    float* out = (float*)d_out;

    float* ws = (float*)d_ws;
    float* q_inv  = ws;                         // 2,048 f
    float* qc_inv = ws + 2048;                  // 2,048 f
    unsigned short* qe_frag  = (unsigned short*)(ws + 4096);      // 655,360 sh (16B-aligned)
    unsigned short* qc_frag  = qe_frag + 655360;                  // 524,288 sh
    unsigned short* filt_frag = qc_frag + 524288;                 // 237,568 sh  (total ~2.85 MB)

    k_fprep<<<928, 256, 0, stream>>>(filters, filt_frag);
    k_qprep<<<VB, 512, 0, stream>>>(question, embeds, filt_frag, qe_frag, qc_frag, q_inv, qc_inv);
    k_sent<<<VB * NSS, 512, 0, stream>>>(sentences, question, embeds,
                                         filt_frag, qe_frag, qc_frag,
                                         q_inv, qc_inv, W6, b1, out);
    k_final<<<1, 256, 0, stream>>>(tsent, tdoc, out);
}